// Round 1
// baseline (404.003 us; speedup 1.0000x reference)
//
#include <hip/hip_runtime.h>
#include <hip/hip_bf16.h>
#include <math.h>

// Problem constants
#define HDIM 1024      // hidden
#define TOK 2048       // B*S tokens
#define NHEAD 8
#define KD 128
#define NKEY 256
#define KSEL 8
#define NQ 2048        // 2*NH*KD
#define BN_EPS 1e-5f

// ---------------- K1: BatchNorm partial sums ----------------
// 64 blocks x 256 threads; block b handles rows 32b..32b+31, thread t columns t, t+256, t+512, t+768
__global__ __launch_bounds__(256) void bn_partial_k(const float* __restrict__ x,
                                                    float* __restrict__ psum,
                                                    float* __restrict__ psq) {
    int b = blockIdx.x;
    int t = threadIdx.x;
    float s[4] = {0.f, 0.f, 0.f, 0.f};
    float s2[4] = {0.f, 0.f, 0.f, 0.f};
    int r0 = b * 32;
    for (int r = 0; r < 32; ++r) {
        const float* row = x + (size_t)(r0 + r) * HDIM;
#pragma unroll
        for (int j = 0; j < 4; ++j) {
            float v = row[t + j * 256];
            s[j] += v;
            s2[j] += v * v;
        }
    }
#pragma unroll
    for (int j = 0; j < 4; ++j) {
        psum[b * HDIM + t + j * 256] = s[j];
        psq[b * HDIM + t + j * 256] = s2[j];
    }
}

// ---------------- K2: finalize scale/shift ----------------
__global__ __launch_bounds__(256) void bn_final_k(const float* __restrict__ psum,
                                                  const float* __restrict__ psq,
                                                  const float* __restrict__ gamma,
                                                  const float* __restrict__ beta,
                                                  float* __restrict__ scale,
                                                  float* __restrict__ shift) {
    int c = blockIdx.x * 256 + threadIdx.x;  // 0..1023
    float s = 0.f, s2 = 0.f;
    for (int b = 0; b < 64; ++b) {
        s += psum[b * HDIM + c];
        s2 += psq[b * HDIM + c];
    }
    float mean = s * (1.0f / TOK);
    float var = s2 * (1.0f / TOK) - mean * mean;
    float sc = gamma[c] * rsqrtf(var + BN_EPS);
    scale[c] = sc;
    shift[c] = beta[c] - mean * sc;
}

// ---------------- K3: tiled fp32 GEMM ----------------
// C[M,N] = A'[M,K] * B[N,K]^T   (both A and B row-major over K)
// MODE 0: A = x (normalized on the fly with scale/shift), B = w_q. Grid (16,16,1).
// MODE 1: batched sim GEMM over z = 16 (p,h) pairs. A = q slice, B = keys slice. Grid (16,2,16).
// 512 threads; 128x128 tile, BK=16; each thread computes 8x4.
template <int MODE>
__global__ __launch_bounds__(512) void gemm_k(const float* __restrict__ A,
                                              const float* __restrict__ Bm,
                                              float* __restrict__ C,
                                              const float* __restrict__ scale,
                                              const float* __restrict__ shift,
                                              int lda, int ldb, int ldc, int K) {
    __shared__ __align__(16) float As[16][128];
    __shared__ __align__(16) float Bs[16][128];
    const float* Ab = A;
    const float* Bb = Bm;
    float* Cb = C;
    if (MODE == 1) {
        int z = blockIdx.z;
        int p = z >> 3, h = z & 7;
        Ab += p * 1024 + h * 128;       // q col offset
        Bb += h * 65536 + p * 128;      // keys_p[h, :, p, :]
        Cb += p * 2048 + h * 256;       // sim[t][p][h][k] within 4096-wide row
    }
    const int m0 = blockIdx.x * 128;
    const int n0 = blockIdx.y * 128;
    const int tid = threadIdx.x;
    const int lr = tid >> 2;        // 0..127
    const int lc = (tid & 3) * 4;   // 0,4,8,12
    const int tm = tid >> 5;        // 0..15
    const int tn = tid & 31;        // 0..31

    float acc[8][4] = {};

    for (int kt = 0; kt < K; kt += 16) {
        float4 av = *(const float4*)(Ab + (size_t)(m0 + lr) * lda + kt + lc);
        if (MODE == 0) {
            float4 s4 = *(const float4*)(scale + kt + lc);
            float4 h4 = *(const float4*)(shift + kt + lc);
            av.x = fmaf(av.x, s4.x, h4.x);
            av.y = fmaf(av.y, s4.y, h4.y);
            av.z = fmaf(av.z, s4.z, h4.z);
            av.w = fmaf(av.w, s4.w, h4.w);
        }
        float4 bv = *(const float4*)(Bb + (size_t)(n0 + lr) * ldb + kt + lc);
        __syncthreads();
        As[lc + 0][lr] = av.x;
        As[lc + 1][lr] = av.y;
        As[lc + 2][lr] = av.z;
        As[lc + 3][lr] = av.w;
        Bs[lc + 0][lr] = bv.x;
        Bs[lc + 1][lr] = bv.y;
        Bs[lc + 2][lr] = bv.z;
        Bs[lc + 3][lr] = bv.w;
        __syncthreads();
#pragma unroll
        for (int kk = 0; kk < 16; ++kk) {
            float4 a0 = *(const float4*)&As[kk][tm * 8];
            float4 a1 = *(const float4*)&As[kk][tm * 8 + 4];
            float4 b0 = *(const float4*)&Bs[kk][tn * 4];
            float a[8] = {a0.x, a0.y, a0.z, a0.w, a1.x, a1.y, a1.z, a1.w};
            float b[4] = {b0.x, b0.y, b0.z, b0.w};
#pragma unroll
            for (int i = 0; i < 8; ++i)
#pragma unroll
                for (int j = 0; j < 4; ++j) acc[i][j] = fmaf(a[i], b[j], acc[i][j]);
        }
    }
#pragma unroll
    for (int i = 0; i < 8; ++i) {
        float4 o = make_float4(acc[i][0], acc[i][1], acc[i][2], acc[i][3]);
        *(float4*)(Cb + (size_t)(m0 + tm * 8 + i) * ldc + n0 + tn * 4) = o;
    }
}

// ---------------- K4: top-k per (token, head) ----------------
// sim layout: sim[t][p*2048 + h*256 + k], row stride 4096.
// One wave per (token, head): 2048 blocks x 512 threads (8 waves).
__global__ __launch_bounds__(512) void topk_k(const float* __restrict__ sim,
                                              int* __restrict__ eidx,
                                              float* __restrict__ gates) {
    int t = blockIdx.x;
    int h = threadIdx.x >> 6;
    int lane = threadIdx.x & 63;
    const float* s0p = sim + (size_t)t * 4096 + h * 256;
    const float* s1p = s0p + 2048;
    float4 v0 = *(const float4*)(s0p + lane * 4);
    float4 v1 = *(const float4*)(s1p + lane * 4);
    float c0[4] = {v0.x, v0.y, v0.z, v0.w};
    float c1[4] = {v1.x, v1.y, v1.z, v1.w};

    float tv0[8], tv1[8];
    int ti0[8], ti1[8];

    // stage-1 top-8 extraction for p=0
#pragma unroll
    for (int r = 0; r < 8; ++r) {
        float bv = c0[0];
        int bi = lane * 4;
#pragma unroll
        for (int j = 1; j < 4; ++j)
            if (c0[j] > bv) { bv = c0[j]; bi = lane * 4 + j; }
#pragma unroll
        for (int off = 1; off < 64; off <<= 1) {
            float ov = __shfl_xor(bv, off);
            int oi = __shfl_xor(bi, off);
            if (ov > bv || (ov == bv && oi < bi)) { bv = ov; bi = oi; }
        }
        tv0[r] = bv;
        ti0[r] = bi;
        if ((bi >> 2) == lane) {
            int jj = bi & 3;
#pragma unroll
            for (int q = 0; q < 4; ++q)
                if (q == jj) c0[q] = -INFINITY;
        }
    }
    // stage-1 top-8 extraction for p=1
#pragma unroll
    for (int r = 0; r < 8; ++r) {
        float bv = c1[0];
        int bi = lane * 4;
#pragma unroll
        for (int j = 1; j < 4; ++j)
            if (c1[j] > bv) { bv = c1[j]; bi = lane * 4 + j; }
#pragma unroll
        for (int off = 1; off < 64; off <<= 1) {
            float ov = __shfl_xor(bv, off);
            int oi = __shfl_xor(bi, off);
            if (ov > bv || (ov == bv && oi < bi)) { bv = ov; bi = oi; }
        }
        tv1[r] = bv;
        ti1[r] = bi;
        if ((bi >> 2) == lane) {
            int jj = bi & 3;
#pragma unroll
            for (int q = 0; q < 4; ++q)
                if (q == jj) c1[q] = -INFINITY;
        }
    }

    // cartesian combine: lane l holds pair (i=l>>3, j=l&7)
    int ii = lane >> 3, jj = lane & 7;
    float a = -INFINITY, b = -INFINITY;
#pragma unroll
    for (int r = 0; r < 8; ++r) {
        if (ii == r) a = tv0[r];
        if (jj == r) b = tv1[r];
    }
    float cv = a + b;
    int cpos = lane;  // position in flattened (8,8), tie-break key

    int outbase = (t * NHEAD + h) * KSEL;
    // stage-2 top-8 of 64
#pragma unroll
    for (int r = 0; r < 8; ++r) {
        float bv = cv;
        int bp = cpos;
#pragma unroll
        for (int off = 1; off < 64; off <<= 1) {
            float ov = __shfl_xor(bv, off);
            int op = __shfl_xor(bp, off);
            if (ov > bv || (ov == bv && op < bp)) { bv = ov; bp = op; }
        }
        if (lane == 0) {
            int pi = bp >> 3, pj = bp & 7;
            int e0 = 0, e1 = 0;
#pragma unroll
            for (int q = 0; q < 8; ++q) {
                if (pi == q) e0 = ti0[q];
                if (pj == q) e1 = ti1[q];
            }
            eidx[outbase + r] = e0 * NKEY + e1;
            gates[outbase + r] = 1.0f / (1.0f + expf(-bv));
        }
        if (lane == bp) cv = -INFINITY;
    }
}

// ---------------- K5: expert gather + compute ----------------
// One block per token, 4 waves x 16 experts each. Full fp32.
__global__ __launch_bounds__(256) void expert_k(const float* __restrict__ x,
                                                const float* __restrict__ down,
                                                const float* __restrict__ up,
                                                const int* __restrict__ eidx,
                                                const float* __restrict__ gates,
                                                float* __restrict__ out) {
    int t = blockIdx.x;
    int w = threadIdx.x >> 6;
    int lane = threadIdx.x & 63;
    __shared__ __align__(16) float4 accs[4][256];

    const float4* x4 = (const float4*)(x + (size_t)t * HDIM);
    float4 xv[4];
#pragma unroll
    for (int j = 0; j < 4; ++j) xv[j] = x4[lane + 64 * j];

    float4 acc[4];
#pragma unroll
    for (int j = 0; j < 4; ++j) acc[j] = make_float4(0.f, 0.f, 0.f, 0.f);

    for (int i = 0; i < 16; ++i) {
        int slot = w * 16 + i;  // 0..63
        int e = eidx[t * 64 + slot];
        float g = gates[t * 64 + slot];
        const float4* d4 = (const float4*)(down + (size_t)e * HDIM);
        const float4* u4 = (const float4*)(up + (size_t)e * HDIM);
        float dot = 0.f;
#pragma unroll
        for (int j = 0; j < 4; ++j) {
            float4 dv = d4[lane + 64 * j];
            dot += xv[j].x * dv.x + xv[j].y * dv.y + xv[j].z * dv.z + xv[j].w * dv.w;
        }
#pragma unroll
        for (int off = 32; off >= 1; off >>= 1) dot += __shfl_xor(dot, off);
        float ge = 0.5f * dot * (1.0f + erff(dot * 0.70710678118654752f));
        float hm = g * ge;
#pragma unroll
        for (int j = 0; j < 4; ++j) {
            float4 uv = u4[lane + 64 * j];
            acc[j].x = fmaf(hm, uv.x, acc[j].x);
            acc[j].y = fmaf(hm, uv.y, acc[j].y);
            acc[j].z = fmaf(hm, uv.z, acc[j].z);
            acc[j].w = fmaf(hm, uv.w, acc[j].w);
        }
    }
#pragma unroll
    for (int j = 0; j < 4; ++j) accs[w][lane + 64 * j] = acc[j];
    __syncthreads();
    int s = threadIdx.x;  // 0..255
    float4 r0 = accs[0][s], r1 = accs[1][s], r2 = accs[2][s], r3 = accs[3][s];
    float4 o;
    o.x = (r0.x + r1.x) + (r2.x + r3.x);
    o.y = (r0.y + r1.y) + (r2.y + r3.y);
    o.z = (r0.z + r1.z) + (r2.z + r3.z);
    o.w = (r0.w + r1.w) + (r2.w + r3.w);
    ((float4*)(out + (size_t)t * HDIM))[s] = o;
}

// ---------------- launch ----------------
extern "C" void kernel_launch(void* const* d_in, const int* in_sizes, int n_in,
                              void* d_out, int out_size, void* d_ws, size_t ws_size,
                              hipStream_t stream) {
    const float* x = (const float*)d_in[0];
    const float* gamma = (const float*)d_in[1];
    const float* beta = (const float*)d_in[2];
    const float* w_q = (const float*)d_in[3];
    const float* keys = (const float*)d_in[4];
    const float* down = (const float*)d_in[5];
    const float* up = (const float*)d_in[6];
    float* out = (float*)d_out;
    float* ws = (float*)d_ws;

    // ws layout (floats):
    float* psum = ws;                       // 64*1024
    float* psq = ws + 65536;                // 64*1024
    float* scale = ws + 131072;             // 1024
    float* shift = ws + 132096;             // 1024
    float* q = ws + 262144;                 // 2048*2048 = 4194304
    float* sim = q + 4194304;               // 2048*4096 = 8388608
    int* eidx = (int*)(sim + 8388608);      // 2048*64
    float* gates = (float*)(eidx + 131072); // 2048*64

    bn_partial_k<<<64, 256, 0, stream>>>(x, psum, psq);
    bn_final_k<<<4, 256, 0, stream>>>(psum, psq, gamma, beta, scale, shift);
    // q = xn @ w_q^T : M=2048, N=2048, K=1024
    gemm_k<0><<<dim3(16, 16, 1), 512, 0, stream>>>(x, w_q, q, scale, shift,
                                                   1024, 1024, 2048, 1024);
    // sim: 16 (p,h) batches, M=2048, N=256, K=128
    gemm_k<1><<<dim3(16, 2, 16), 512, 0, stream>>>(q, keys, sim, nullptr, nullptr,
                                                   2048, 256, 4096, 128);
    topk_k<<<2048, 512, 0, stream>>>(sim, eidx, gates);
    expert_k<<<2048, 256, 0, stream>>>(x, down, up, eidx, gates, out);
}

// Round 2
// 398.639 us; speedup vs baseline: 1.0135x; 1.0135x over previous
//
#include <hip/hip_runtime.h>
#include <hip/hip_bf16.h>
#include <math.h>

// Problem constants
#define HDIM 1024      // hidden
#define TOK 2048       // B*S tokens
#define NHEAD 8
#define KD 128
#define NKEY 256
#define KSEL 8
#define NQ 2048        // 2*NH*KD
#define BN_EPS 1e-5f

// ---------------- K1: BatchNorm partial sums ----------------
__global__ __launch_bounds__(256) void bn_partial_k(const float* __restrict__ x,
                                                    float* __restrict__ psum,
                                                    float* __restrict__ psq) {
    int b = blockIdx.x;
    int t = threadIdx.x;
    float s[4] = {0.f, 0.f, 0.f, 0.f};
    float s2[4] = {0.f, 0.f, 0.f, 0.f};
    int r0 = b * 32;
    for (int r = 0; r < 32; ++r) {
        const float* row = x + (size_t)(r0 + r) * HDIM;
#pragma unroll
        for (int j = 0; j < 4; ++j) {
            float v = row[t + j * 256];
            s[j] += v;
            s2[j] += v * v;
        }
    }
#pragma unroll
    for (int j = 0; j < 4; ++j) {
        psum[b * HDIM + t + j * 256] = s[j];
        psq[b * HDIM + t + j * 256] = s2[j];
    }
}

// ---------------- K2: finalize scale/shift ----------------
__global__ __launch_bounds__(256) void bn_final_k(const float* __restrict__ psum,
                                                  const float* __restrict__ psq,
                                                  const float* __restrict__ gamma,
                                                  const float* __restrict__ beta,
                                                  float* __restrict__ scale,
                                                  float* __restrict__ shift) {
    int c = blockIdx.x * 256 + threadIdx.x;  // 0..1023
    float s = 0.f, s2 = 0.f;
    for (int b = 0; b < 64; ++b) {
        s += psum[b * HDIM + c];
        s2 += psq[b * HDIM + c];
    }
    float mean = s * (1.0f / TOK);
    float var = s2 * (1.0f / TOK) - mean * mean;
    float sc = gamma[c] * rsqrtf(var + BN_EPS);
    scale[c] = sc;
    shift[c] = beta[c] - mean * sc;
}

// ---------------- K3: tiled fp32 GEMM ----------------
// C[M,N] = A'[M,K] * B[N,K]^T   (both A and B row-major over K)
// MODE 0: A = x (normalized on the fly with scale/shift), B = w_q. Grid (16,16,1).
// MODE 1: batched sim GEMM over z = 16 (p,h) pairs. Grid (16,2,16).
template <int MODE>
__global__ __launch_bounds__(512) void gemm_k(const float* __restrict__ A,
                                              const float* __restrict__ Bm,
                                              float* __restrict__ C,
                                              const float* __restrict__ scale,
                                              const float* __restrict__ shift,
                                              int lda, int ldb, int ldc, int K) {
    __shared__ __align__(16) float As[16][128];
    __shared__ __align__(16) float Bs[16][128];
    const float* Ab = A;
    const float* Bb = Bm;
    float* Cb = C;
    if (MODE == 1) {
        int z = blockIdx.z;
        int p = z >> 3, h = z & 7;
        Ab += p * 1024 + h * 128;       // q col offset
        Bb += h * 65536 + p * 128;      // keys_p[h, :, p, :]
        Cb += p * 2048 + h * 256;       // sim[t][p][h][k] within 4096-wide row
    }
    const int m0 = blockIdx.x * 128;
    const int n0 = blockIdx.y * 128;
    const int tid = threadIdx.x;
    const int lr = tid >> 2;        // 0..127
    const int lc = (tid & 3) * 4;   // 0,4,8,12
    const int tm = tid >> 5;        // 0..15
    const int tn = tid & 31;        // 0..31

    float acc[8][4] = {};

    for (int kt = 0; kt < K; kt += 16) {
        float4 av = *(const float4*)(Ab + (size_t)(m0 + lr) * lda + kt + lc);
        if (MODE == 0) {
            float4 s4 = *(const float4*)(scale + kt + lc);
            float4 h4 = *(const float4*)(shift + kt + lc);
            av.x = fmaf(av.x, s4.x, h4.x);
            av.y = fmaf(av.y, s4.y, h4.y);
            av.z = fmaf(av.z, s4.z, h4.z);
            av.w = fmaf(av.w, s4.w, h4.w);
        }
        float4 bv = *(const float4*)(Bb + (size_t)(n0 + lr) * ldb + kt + lc);
        __syncthreads();
        As[lc + 0][lr] = av.x;
        As[lc + 1][lr] = av.y;
        As[lc + 2][lr] = av.z;
        As[lc + 3][lr] = av.w;
        Bs[lc + 0][lr] = bv.x;
        Bs[lc + 1][lr] = bv.y;
        Bs[lc + 2][lr] = bv.z;
        Bs[lc + 3][lr] = bv.w;
        __syncthreads();
#pragma unroll
        for (int kk = 0; kk < 16; ++kk) {
            float4 a0 = *(const float4*)&As[kk][tm * 8];
            float4 a1 = *(const float4*)&As[kk][tm * 8 + 4];
            float4 b0 = *(const float4*)&Bs[kk][tn * 4];
            float a[8] = {a0.x, a0.y, a0.z, a0.w, a1.x, a1.y, a1.z, a1.w};
            float b[4] = {b0.x, b0.y, b0.z, b0.w};
#pragma unroll
            for (int i = 0; i < 8; ++i)
#pragma unroll
                for (int j = 0; j < 4; ++j) acc[i][j] = fmaf(a[i], b[j], acc[i][j]);
        }
    }
#pragma unroll
    for (int i = 0; i < 8; ++i) {
        float4 o = make_float4(acc[i][0], acc[i][1], acc[i][2], acc[i][3]);
        *(float4*)(Cb + (size_t)(m0 + tm * 8 + i) * ldc + n0 + tn * 4) = o;
    }
}

// ---------------- K4: top-k per (token, head) ----------------
__global__ __launch_bounds__(512) void topk_k(const float* __restrict__ sim,
                                              int* __restrict__ eidx,
                                              float* __restrict__ gates) {
    int t = blockIdx.x;
    int h = threadIdx.x >> 6;
    int lane = threadIdx.x & 63;
    const float* s0p = sim + (size_t)t * 4096 + h * 256;
    const float* s1p = s0p + 2048;
    float4 v0 = *(const float4*)(s0p + lane * 4);
    float4 v1 = *(const float4*)(s1p + lane * 4);
    float c0[4] = {v0.x, v0.y, v0.z, v0.w};
    float c1[4] = {v1.x, v1.y, v1.z, v1.w};

    float tv0[8], tv1[8];
    int ti0[8], ti1[8];

#pragma unroll
    for (int r = 0; r < 8; ++r) {
        float bv = c0[0];
        int bi = lane * 4;
#pragma unroll
        for (int j = 1; j < 4; ++j)
            if (c0[j] > bv) { bv = c0[j]; bi = lane * 4 + j; }
#pragma unroll
        for (int off = 1; off < 64; off <<= 1) {
            float ov = __shfl_xor(bv, off);
            int oi = __shfl_xor(bi, off);
            if (ov > bv || (ov == bv && oi < bi)) { bv = ov; bi = oi; }
        }
        tv0[r] = bv;
        ti0[r] = bi;
        if ((bi >> 2) == lane) {
            int jj = bi & 3;
#pragma unroll
            for (int q = 0; q < 4; ++q)
                if (q == jj) c0[q] = -INFINITY;
        }
    }
#pragma unroll
    for (int r = 0; r < 8; ++r) {
        float bv = c1[0];
        int bi = lane * 4;
#pragma unroll
        for (int j = 1; j < 4; ++j)
            if (c1[j] > bv) { bv = c1[j]; bi = lane * 4 + j; }
#pragma unroll
        for (int off = 1; off < 64; off <<= 1) {
            float ov = __shfl_xor(bv, off);
            int oi = __shfl_xor(bi, off);
            if (ov > bv || (ov == bv && oi < bi)) { bv = ov; bi = oi; }
        }
        tv1[r] = bv;
        ti1[r] = bi;
        if ((bi >> 2) == lane) {
            int jj = bi & 3;
#pragma unroll
            for (int q = 0; q < 4; ++q)
                if (q == jj) c1[q] = -INFINITY;
        }
    }

    int ii = lane >> 3, jj = lane & 7;
    float a = -INFINITY, b = -INFINITY;
#pragma unroll
    for (int r = 0; r < 8; ++r) {
        if (ii == r) a = tv0[r];
        if (jj == r) b = tv1[r];
    }
    float cv = a + b;
    int cpos = lane;

    int outbase = (t * NHEAD + h) * KSEL;
#pragma unroll
    for (int r = 0; r < 8; ++r) {
        float bv = cv;
        int bp = cpos;
#pragma unroll
        for (int off = 1; off < 64; off <<= 1) {
            float ov = __shfl_xor(bv, off);
            int op = __shfl_xor(bp, off);
            if (ov > bv || (ov == bv && op < bp)) { bv = ov; bp = op; }
        }
        if (lane == 0) {
            int pi = bp >> 3, pj = bp & 7;
            int e0 = 0, e1 = 0;
#pragma unroll
            for (int q = 0; q < 8; ++q) {
                if (pi == q) e0 = ti0[q];
                if (pj == q) e1 = ti1[q];
            }
            eidx[outbase + r] = e0 * NKEY + e1;
            gates[outbase + r] = 1.0f / (1.0f + expf(-bv));
        }
        if (lane == bp) cv = -INFINITY;
    }
}

// ---------------- K5: expert gather + compute ----------------
// One block per token, 8 waves x 8 experts each, pair-unrolled for MLP.
// All 16 float4 loads (down0,down1,up0,up1) issued before dependent compute.
__global__ __launch_bounds__(512) void expert_k(const float* __restrict__ x,
                                                const float* __restrict__ down,
                                                const float* __restrict__ up,
                                                const int* __restrict__ eidx,
                                                const float* __restrict__ gates,
                                                float* __restrict__ out) {
    int t = blockIdx.x;
    int w = threadIdx.x >> 6;      // 0..7
    int lane = threadIdx.x & 63;
    __shared__ __align__(16) float4 accs[8][256];

    const float4* x4 = (const float4*)(x + (size_t)t * HDIM);
    float4 xv[4];
#pragma unroll
    for (int j = 0; j < 4; ++j) xv[j] = x4[lane + 64 * j];

    float4 acc[4];
#pragma unroll
    for (int j = 0; j < 4; ++j) acc[j] = make_float4(0.f, 0.f, 0.f, 0.f);

    int base = t * 64 + w * 8;
#pragma unroll
    for (int i = 0; i < 8; i += 2) {
        int e0 = eidx[base + i];
        int e1 = eidx[base + i + 1];
        float g0 = gates[base + i];
        float g1 = gates[base + i + 1];
        const float4* d0 = (const float4*)(down + (size_t)e0 * HDIM);
        const float4* d1 = (const float4*)(down + (size_t)e1 * HDIM);
        const float4* u0 = (const float4*)(up + (size_t)e0 * HDIM);
        const float4* u1 = (const float4*)(up + (size_t)e1 * HDIM);
        float4 dv0[4], dv1[4], uv0[4], uv1[4];
#pragma unroll
        for (int j = 0; j < 4; ++j) {
            dv0[j] = d0[lane + 64 * j];
            dv1[j] = d1[lane + 64 * j];
            uv0[j] = u0[lane + 64 * j];
            uv1[j] = u1[lane + 64 * j];
        }
        float dot0 = 0.f, dot1 = 0.f;
#pragma unroll
        for (int j = 0; j < 4; ++j) {
            dot0 += xv[j].x * dv0[j].x + xv[j].y * dv0[j].y + xv[j].z * dv0[j].z + xv[j].w * dv0[j].w;
            dot1 += xv[j].x * dv1[j].x + xv[j].y * dv1[j].y + xv[j].z * dv1[j].z + xv[j].w * dv1[j].w;
        }
#pragma unroll
        for (int off = 32; off >= 1; off >>= 1) {
            dot0 += __shfl_xor(dot0, off);
            dot1 += __shfl_xor(dot1, off);
        }
        float ge0 = 0.5f * dot0 * (1.0f + erff(dot0 * 0.70710678118654752f));
        float ge1 = 0.5f * dot1 * (1.0f + erff(dot1 * 0.70710678118654752f));
        float hm0 = g0 * ge0;
        float hm1 = g1 * ge1;
#pragma unroll
        for (int j = 0; j < 4; ++j) {
            acc[j].x = fmaf(hm0, uv0[j].x, fmaf(hm1, uv1[j].x, acc[j].x));
            acc[j].y = fmaf(hm0, uv0[j].y, fmaf(hm1, uv1[j].y, acc[j].y));
            acc[j].z = fmaf(hm0, uv0[j].z, fmaf(hm1, uv1[j].z, acc[j].z));
            acc[j].w = fmaf(hm0, uv0[j].w, fmaf(hm1, uv1[j].w, acc[j].w));
        }
    }
#pragma unroll
    for (int j = 0; j < 4; ++j) accs[w][lane + 64 * j] = acc[j];
    __syncthreads();
    if (threadIdx.x < 256) {
        int s = threadIdx.x;
        float4 o = accs[0][s];
#pragma unroll
        for (int ww = 1; ww < 8; ++ww) {
            float4 r = accs[ww][s];
            o.x += r.x; o.y += r.y; o.z += r.z; o.w += r.w;
        }
        ((float4*)(out + (size_t)t * HDIM))[s] = o;
    }
}

// ---------------- launch ----------------
extern "C" void kernel_launch(void* const* d_in, const int* in_sizes, int n_in,
                              void* d_out, int out_size, void* d_ws, size_t ws_size,
                              hipStream_t stream) {
    const float* x = (const float*)d_in[0];
    const float* gamma = (const float*)d_in[1];
    const float* beta = (const float*)d_in[2];
    const float* w_q = (const float*)d_in[3];
    const float* keys = (const float*)d_in[4];
    const float* down = (const float*)d_in[5];
    const float* up = (const float*)d_in[6];
    float* out = (float*)d_out;
    float* ws = (float*)d_ws;

    float* psum = ws;                       // 64*1024
    float* psq = ws + 65536;                // 64*1024
    float* scale = ws + 131072;             // 1024
    float* shift = ws + 132096;             // 1024
    float* q = ws + 262144;                 // 2048*2048 = 4194304
    float* sim = q + 4194304;               // 2048*4096 = 8388608
    int* eidx = (int*)(sim + 8388608);      // 2048*64
    float* gates = (float*)(eidx + 131072); // 2048*64

    bn_partial_k<<<64, 256, 0, stream>>>(x, psum, psq);
    bn_final_k<<<4, 256, 0, stream>>>(psum, psq, gamma, beta, scale, shift);
    gemm_k<0><<<dim3(16, 16, 1), 512, 0, stream>>>(x, w_q, q, scale, shift,
                                                   1024, 1024, 2048, 1024);
    gemm_k<1><<<dim3(16, 2, 16), 512, 0, stream>>>(q, keys, sim, nullptr, nullptr,
                                                   2048, 256, 4096, 128);
    topk_k<<<2048, 512, 0, stream>>>(sim, eidx, gates);
    expert_k<<<2048, 512, 0, stream>>>(x, down, up, eidx, gates, out);
}

// Round 3
// 397.464 us; speedup vs baseline: 1.0165x; 1.0030x over previous
//
#include <hip/hip_runtime.h>
#include <hip/hip_bf16.h>
#include <math.h>

// Problem constants
#define HDIM 1024      // hidden
#define TOK 2048       // B*S tokens
#define NHEAD 8
#define KD 128
#define NKEY 256
#define KSEL 8
#define NQ 2048        // 2*NH*KD
#define BN_EPS 1e-5f

// ---------------- K1: BatchNorm partial sums ----------------
__global__ __launch_bounds__(256) void bn_partial_k(const float* __restrict__ x,
                                                    float* __restrict__ psum,
                                                    float* __restrict__ psq) {
    int b = blockIdx.x;
    int t = threadIdx.x;
    float s[4] = {0.f, 0.f, 0.f, 0.f};
    float s2[4] = {0.f, 0.f, 0.f, 0.f};
    int r0 = b * 32;
    for (int r = 0; r < 32; ++r) {
        const float* row = x + (size_t)(r0 + r) * HDIM;
#pragma unroll
        for (int j = 0; j < 4; ++j) {
            float v = row[t + j * 256];
            s[j] += v;
            s2[j] += v * v;
        }
    }
#pragma unroll
    for (int j = 0; j < 4; ++j) {
        psum[b * HDIM + t + j * 256] = s[j];
        psq[b * HDIM + t + j * 256] = s2[j];
    }
}

// ---------------- K2: finalize scale/shift ----------------
__global__ __launch_bounds__(256) void bn_final_k(const float* __restrict__ psum,
                                                  const float* __restrict__ psq,
                                                  const float* __restrict__ gamma,
                                                  const float* __restrict__ beta,
                                                  float* __restrict__ scale,
                                                  float* __restrict__ shift) {
    int c = blockIdx.x * 256 + threadIdx.x;  // 0..1023
    float s = 0.f, s2 = 0.f;
    for (int b = 0; b < 64; ++b) {
        s += psum[b * HDIM + c];
        s2 += psq[b * HDIM + c];
    }
    float mean = s * (1.0f / TOK);
    float var = s2 * (1.0f / TOK) - mean * mean;
    float sc = gamma[c] * rsqrtf(var + BN_EPS);
    scale[c] = sc;
    shift[c] = beta[c] - mean * sc;
}

// ---------------- K3: tiled fp32 GEMM ----------------
// C[M,N] = A'[M,K] * B[N,K]^T   (both A and B row-major over K)
// MODE 0: A = x (normalized on the fly with scale/shift), B = w_q. Grid (16,16,1).
// MODE 1: batched sim GEMM over z = 16 (p,h) pairs. Grid (16,2,16).
template <int MODE>
__global__ __launch_bounds__(512) void gemm_k(const float* __restrict__ A,
                                              const float* __restrict__ Bm,
                                              float* __restrict__ C,
                                              const float* __restrict__ scale,
                                              const float* __restrict__ shift,
                                              int lda, int ldb, int ldc, int K) {
    __shared__ __align__(16) float As[16][128];
    __shared__ __align__(16) float Bs[16][128];
    const float* Ab = A;
    const float* Bb = Bm;
    float* Cb = C;
    if (MODE == 1) {
        int z = blockIdx.z;
        int p = z >> 3, h = z & 7;
        Ab += p * 1024 + h * 128;       // q col offset
        Bb += h * 65536 + p * 128;      // keys_p[h, :, p, :]
        Cb += p * 2048 + h * 256;       // sim[t][p][h][k] within 4096-wide row
    }
    const int m0 = blockIdx.x * 128;
    const int n0 = blockIdx.y * 128;
    const int tid = threadIdx.x;
    const int lr = tid >> 2;        // 0..127
    const int lc = (tid & 3) * 4;   // 0,4,8,12
    const int tm = tid >> 5;        // 0..15
    const int tn = tid & 31;        // 0..31

    float acc[8][4] = {};

    for (int kt = 0; kt < K; kt += 16) {
        float4 av = *(const float4*)(Ab + (size_t)(m0 + lr) * lda + kt + lc);
        if (MODE == 0) {
            float4 s4 = *(const float4*)(scale + kt + lc);
            float4 h4 = *(const float4*)(shift + kt + lc);
            av.x = fmaf(av.x, s4.x, h4.x);
            av.y = fmaf(av.y, s4.y, h4.y);
            av.z = fmaf(av.z, s4.z, h4.z);
            av.w = fmaf(av.w, s4.w, h4.w);
        }
        float4 bv = *(const float4*)(Bb + (size_t)(n0 + lr) * ldb + kt + lc);
        __syncthreads();
        As[lc + 0][lr] = av.x;
        As[lc + 1][lr] = av.y;
        As[lc + 2][lr] = av.z;
        As[lc + 3][lr] = av.w;
        Bs[lc + 0][lr] = bv.x;
        Bs[lc + 1][lr] = bv.y;
        Bs[lc + 2][lr] = bv.z;
        Bs[lc + 3][lr] = bv.w;
        __syncthreads();
#pragma unroll
        for (int kk = 0; kk < 16; ++kk) {
            float4 a0 = *(const float4*)&As[kk][tm * 8];
            float4 a1 = *(const float4*)&As[kk][tm * 8 + 4];
            float4 b0 = *(const float4*)&Bs[kk][tn * 4];
            float a[8] = {a0.x, a0.y, a0.z, a0.w, a1.x, a1.y, a1.z, a1.w};
            float b[4] = {b0.x, b0.y, b0.z, b0.w};
#pragma unroll
            for (int i = 0; i < 8; ++i)
#pragma unroll
                for (int j = 0; j < 4; ++j) acc[i][j] = fmaf(a[i], b[j], acc[i][j]);
        }
    }
#pragma unroll
    for (int i = 0; i < 8; ++i) {
        float4 o = make_float4(acc[i][0], acc[i][1], acc[i][2], acc[i][3]);
        *(float4*)(Cb + (size_t)(m0 + tm * 8 + i) * ldc + n0 + tn * 4) = o;
    }
}

// ---------------- K4: top-k per (token, head) ----------------
__global__ __launch_bounds__(512) void topk_k(const float* __restrict__ sim,
                                              int* __restrict__ eidx,
                                              float* __restrict__ gates) {
    int t = blockIdx.x;
    int h = threadIdx.x >> 6;
    int lane = threadIdx.x & 63;
    const float* s0p = sim + (size_t)t * 4096 + h * 256;
    const float* s1p = s0p + 2048;
    float4 v0 = *(const float4*)(s0p + lane * 4);
    float4 v1 = *(const float4*)(s1p + lane * 4);
    float c0[4] = {v0.x, v0.y, v0.z, v0.w};
    float c1[4] = {v1.x, v1.y, v1.z, v1.w};

    float tv0[8], tv1[8];
    int ti0[8], ti1[8];

#pragma unroll
    for (int r = 0; r < 8; ++r) {
        float bv = c0[0];
        int bi = lane * 4;
#pragma unroll
        for (int j = 1; j < 4; ++j)
            if (c0[j] > bv) { bv = c0[j]; bi = lane * 4 + j; }
#pragma unroll
        for (int off = 1; off < 64; off <<= 1) {
            float ov = __shfl_xor(bv, off);
            int oi = __shfl_xor(bi, off);
            if (ov > bv || (ov == bv && oi < bi)) { bv = ov; bi = oi; }
        }
        tv0[r] = bv;
        ti0[r] = bi;
        if ((bi >> 2) == lane) {
            int jj = bi & 3;
#pragma unroll
            for (int q = 0; q < 4; ++q)
                if (q == jj) c0[q] = -INFINITY;
        }
    }
#pragma unroll
    for (int r = 0; r < 8; ++r) {
        float bv = c1[0];
        int bi = lane * 4;
#pragma unroll
        for (int j = 1; j < 4; ++j)
            if (c1[j] > bv) { bv = c1[j]; bi = lane * 4 + j; }
#pragma unroll
        for (int off = 1; off < 64; off <<= 1) {
            float ov = __shfl_xor(bv, off);
            int oi = __shfl_xor(bi, off);
            if (ov > bv || (ov == bv && oi < bi)) { bv = ov; bi = oi; }
        }
        tv1[r] = bv;
        ti1[r] = bi;
        if ((bi >> 2) == lane) {
            int jj = bi & 3;
#pragma unroll
            for (int q = 0; q < 4; ++q)
                if (q == jj) c1[q] = -INFINITY;
        }
    }

    int ii = lane >> 3, jj = lane & 7;
    float a = -INFINITY, b = -INFINITY;
#pragma unroll
    for (int r = 0; r < 8; ++r) {
        if (ii == r) a = tv0[r];
        if (jj == r) b = tv1[r];
    }
    float cv = a + b;
    int cpos = lane;

    int outbase = (t * NHEAD + h) * KSEL;
#pragma unroll
    for (int r = 0; r < 8; ++r) {
        float bv = cv;
        int bp = cpos;
#pragma unroll
        for (int off = 1; off < 64; off <<= 1) {
            float ov = __shfl_xor(bv, off);
            int op = __shfl_xor(bp, off);
            if (ov > bv || (ov == bv && op < bp)) { bv = ov; bp = op; }
        }
        if (lane == 0) {
            int pi = bp >> 3, pj = bp & 7;
            int e0 = 0, e1 = 0;
#pragma unroll
            for (int q = 0; q < 8; ++q) {
                if (pi == q) e0 = ti0[q];
                if (pj == q) e1 = ti1[q];
            }
            eidx[outbase + r] = e0 * NKEY + e1;
            gates[outbase + r] = 1.0f / (1.0f + expf(-bv));
        }
        if (lane == bp) cv = -INFINITY;
    }
}

// ---------------- K5: expert gather + compute ----------------
// One block per token, 8 waves x 8 experts. Three phases per wave:
//  (1) streaming dot phase: 32 independent float4 loads -> 8 per-lane dot accs
//  (2) one batched shuffle reduce (8 parallel trees) + gelu/gate
//  (3) streaming up phase: 32 loads + fma into 4 float4 accs
__global__ __launch_bounds__(512, 2) void expert_k(const float* __restrict__ x,
                                                   const float* __restrict__ down,
                                                   const float* __restrict__ up,
                                                   const int* __restrict__ eidx,
                                                   const float* __restrict__ gates,
                                                   float* __restrict__ out) {
    int t = blockIdx.x;
    int w = threadIdx.x >> 6;      // 0..7
    int lane = threadIdx.x & 63;
    __shared__ __align__(16) float4 accs[8][256];

    const float4* x4 = (const float4*)(x + (size_t)t * HDIM);
    float4 xv[4];
#pragma unroll
    for (int j = 0; j < 4; ++j) xv[j] = x4[lane + 64 * j];

    int base = t * 64 + w * 8;
    int e[8];
    float g[8];
#pragma unroll
    for (int i = 0; i < 8; ++i) {
        e[i] = eidx[base + i];
        g[i] = gates[base + i];
    }

    // Phase 1: per-lane partial dots, 8 independent accumulators
    float dot[8];
#pragma unroll
    for (int i = 0; i < 8; ++i) dot[i] = 0.f;
#pragma unroll
    for (int i = 0; i < 8; ++i) {
        const float4* d = (const float4*)(down + (size_t)e[i] * HDIM);
#pragma unroll
        for (int j = 0; j < 4; ++j) {
            float4 dv = d[lane + 64 * j];
            dot[i] += xv[j].x * dv.x + xv[j].y * dv.y + xv[j].z * dv.z + xv[j].w * dv.w;
        }
    }

    // Phase 2: batched reduce (8 parallel 6-step trees), then gelu*gate
#pragma unroll
    for (int off = 32; off >= 1; off >>= 1) {
#pragma unroll
        for (int i = 0; i < 8; ++i) dot[i] += __shfl_xor(dot[i], off);
    }
    float hm[8];
#pragma unroll
    for (int i = 0; i < 8; ++i) {
        float d = dot[i];
        hm[i] = g[i] * 0.5f * d * (1.0f + erff(d * 0.70710678118654752f));
    }

    // Phase 3: streaming up-row accumulation
    float4 acc[4];
#pragma unroll
    for (int j = 0; j < 4; ++j) acc[j] = make_float4(0.f, 0.f, 0.f, 0.f);
#pragma unroll
    for (int i = 0; i < 8; ++i) {
        const float4* u = (const float4*)(up + (size_t)e[i] * HDIM);
        float h = hm[i];
#pragma unroll
        for (int j = 0; j < 4; ++j) {
            float4 uv = u[lane + 64 * j];
            acc[j].x = fmaf(h, uv.x, acc[j].x);
            acc[j].y = fmaf(h, uv.y, acc[j].y);
            acc[j].z = fmaf(h, uv.z, acc[j].z);
            acc[j].w = fmaf(h, uv.w, acc[j].w);
        }
    }

#pragma unroll
    for (int j = 0; j < 4; ++j) accs[w][lane + 64 * j] = acc[j];
    __syncthreads();
    if (threadIdx.x < 256) {
        int s = threadIdx.x;
        float4 o = accs[0][s];
#pragma unroll
        for (int ww = 1; ww < 8; ++ww) {
            float4 r = accs[ww][s];
            o.x += r.x; o.y += r.y; o.z += r.z; o.w += r.w;
        }
        ((float4*)(out + (size_t)t * HDIM))[s] = o;
    }
}

// ---------------- launch ----------------
extern "C" void kernel_launch(void* const* d_in, const int* in_sizes, int n_in,
                              void* d_out, int out_size, void* d_ws, size_t ws_size,
                              hipStream_t stream) {
    const float* x = (const float*)d_in[0];
    const float* gamma = (const float*)d_in[1];
    const float* beta = (const float*)d_in[2];
    const float* w_q = (const float*)d_in[3];
    const float* keys = (const float*)d_in[4];
    const float* down = (const float*)d_in[5];
    const float* up = (const float*)d_in[6];
    float* out = (float*)d_out;
    float* ws = (float*)d_ws;

    float* psum = ws;                       // 64*1024
    float* psq = ws + 65536;                // 64*1024
    float* scale = ws + 131072;             // 1024
    float* shift = ws + 132096;             // 1024
    float* q = ws + 262144;                 // 2048*2048 = 4194304
    float* sim = q + 4194304;               // 2048*4096 = 8388608
    int* eidx = (int*)(sim + 8388608);      // 2048*64
    float* gates = (float*)(eidx + 131072); // 2048*64

    bn_partial_k<<<64, 256, 0, stream>>>(x, psum, psq);
    bn_final_k<<<4, 256, 0, stream>>>(psum, psq, gamma, beta, scale, shift);
    gemm_k<0><<<dim3(16, 16, 1), 512, 0, stream>>>(x, w_q, q, scale, shift,
                                                   1024, 1024, 2048, 1024);
    gemm_k<1><<<dim3(16, 2, 16), 512, 0, stream>>>(q, keys, sim, nullptr, nullptr,
                                                   2048, 256, 4096, 128);
    topk_k<<<2048, 512, 0, stream>>>(sim, eidx, gates);
    expert_k<<<2048, 512, 0, stream>>>(x, down, up, eidx, gates, out);
}

// Round 4
// 385.737 us; speedup vs baseline: 1.0474x; 1.0304x over previous
//
#include <hip/hip_runtime.h>
#include <hip/hip_bf16.h>
#include <math.h>

// Problem constants
#define HDIM 1024      // hidden
#define TOK 2048       // B*S tokens
#define NHEAD 8
#define KD 128
#define NKEY 256
#define KSEL 8
#define NQ 2048        // 2*NH*KD
#define BN_EPS 1e-5f

// ---------------- K1: BatchNorm partial sums ----------------
__global__ __launch_bounds__(256) void bn_partial_k(const float* __restrict__ x,
                                                    float* __restrict__ psum,
                                                    float* __restrict__ psq) {
    int b = blockIdx.x;
    int t = threadIdx.x;
    float s[4] = {0.f, 0.f, 0.f, 0.f};
    float s2[4] = {0.f, 0.f, 0.f, 0.f};
    int r0 = b * 32;
    for (int r = 0; r < 32; ++r) {
        const float* row = x + (size_t)(r0 + r) * HDIM;
#pragma unroll
        for (int j = 0; j < 4; ++j) {
            float v = row[t + j * 256];
            s[j] += v;
            s2[j] += v * v;
        }
    }
#pragma unroll
    for (int j = 0; j < 4; ++j) {
        psum[b * HDIM + t + j * 256] = s[j];
        psq[b * HDIM + t + j * 256] = s2[j];
    }
}

// ---------------- K2: finalize scale/shift ----------------
__global__ __launch_bounds__(256) void bn_final_k(const float* __restrict__ psum,
                                                  const float* __restrict__ psq,
                                                  const float* __restrict__ gamma,
                                                  const float* __restrict__ beta,
                                                  float* __restrict__ scale,
                                                  float* __restrict__ shift) {
    int c = blockIdx.x * 256 + threadIdx.x;  // 0..1023
    float s = 0.f, s2 = 0.f;
    for (int b = 0; b < 64; ++b) {
        s += psum[b * HDIM + c];
        s2 += psq[b * HDIM + c];
    }
    float mean = s * (1.0f / TOK);
    float var = s2 * (1.0f / TOK) - mean * mean;
    float sc = gamma[c] * rsqrtf(var + BN_EPS);
    scale[c] = sc;
    shift[c] = beta[c] - mean * sc;
}

// ---------------- K3: tiled fp32 GEMM, double-buffered ----------------
// C[M,N] = A'[M,K] * B[N,K]^T   (both A and B row-major over K)
// MODE 0: A = x (normalized on the fly with scale/shift), B = w_q. Grid (16,16,1).
// MODE 1: batched sim GEMM over z = 16 (p,h) pairs. Grid (16,2,16).
// 512 threads; 128x128 tile, BK=16; micro-tile 8x4; LDS ping-pong, one barrier/step.
template <int MODE>
__global__ __launch_bounds__(512) void gemm_k(const float* __restrict__ A,
                                              const float* __restrict__ Bm,
                                              float* __restrict__ C,
                                              const float* __restrict__ scale,
                                              const float* __restrict__ shift,
                                              int lda, int ldb, int ldc, int K) {
    __shared__ __align__(16) float As[2][16][128];
    __shared__ __align__(16) float Bs[2][16][128];
    const float* Ab = A;
    const float* Bb = Bm;
    float* Cb = C;
    if (MODE == 1) {
        int z = blockIdx.z;
        int p = z >> 3, h = z & 7;
        Ab += p * 1024 + h * 128;       // q col offset
        Bb += h * 65536 + p * 128;      // keys_p[h, :, p, :]
        Cb += p * 2048 + h * 256;       // sim[t][p][h][k] within 4096-wide row
    }
    const int m0 = blockIdx.x * 128;
    const int n0 = blockIdx.y * 128;
    const int tid = threadIdx.x;
    const int lr = tid >> 2;        // 0..127
    const int lc = (tid & 3) * 4;   // 0,4,8,12
    const int tm = tid >> 5;        // 0..15
    const int tn = tid & 31;        // 0..31

    float acc[8][4] = {};

    const float* arow = Ab + (size_t)(m0 + lr) * lda + lc;
    const float* brow = Bb + (size_t)(n0 + lr) * ldb + lc;

    // prologue: stage step 0
    {
        float4 av = *(const float4*)(arow);
        if (MODE == 0) {
            float4 s4 = *(const float4*)(scale + lc);
            float4 h4 = *(const float4*)(shift + lc);
            av.x = fmaf(av.x, s4.x, h4.x);
            av.y = fmaf(av.y, s4.y, h4.y);
            av.z = fmaf(av.z, s4.z, h4.z);
            av.w = fmaf(av.w, s4.w, h4.w);
        }
        float4 bv = *(const float4*)(brow);
        As[0][lc + 0][lr] = av.x;
        As[0][lc + 1][lr] = av.y;
        As[0][lc + 2][lr] = av.z;
        As[0][lc + 3][lr] = av.w;
        Bs[0][lc + 0][lr] = bv.x;
        Bs[0][lc + 1][lr] = bv.y;
        Bs[0][lc + 2][lr] = bv.z;
        Bs[0][lc + 3][lr] = bv.w;
    }
    __syncthreads();

    const int NS = K >> 4;
    for (int s = 0; s < NS; ++s) {
        const int buf = s & 1;
        float4 av, bv;
        const bool more = (s + 1) < NS;
        if (more) {
            int kt = (s + 1) << 4;
            av = *(const float4*)(arow + kt);
            if (MODE == 0) {
                float4 s4 = *(const float4*)(scale + kt + lc);
                float4 h4 = *(const float4*)(shift + kt + lc);
                av.x = fmaf(av.x, s4.x, h4.x);
                av.y = fmaf(av.y, s4.y, h4.y);
                av.z = fmaf(av.z, s4.z, h4.z);
                av.w = fmaf(av.w, s4.w, h4.w);
            }
            bv = *(const float4*)(brow + kt);
        }
#pragma unroll
        for (int kk = 0; kk < 16; ++kk) {
            float4 a0 = *(const float4*)&As[buf][kk][tm * 8];
            float4 a1 = *(const float4*)&As[buf][kk][tm * 8 + 4];
            float4 b0 = *(const float4*)&Bs[buf][kk][tn * 4];
            float a[8] = {a0.x, a0.y, a0.z, a0.w, a1.x, a1.y, a1.z, a1.w};
            float b[4] = {b0.x, b0.y, b0.z, b0.w};
#pragma unroll
            for (int i = 0; i < 8; ++i)
#pragma unroll
                for (int j = 0; j < 4; ++j) acc[i][j] = fmaf(a[i], b[j], acc[i][j]);
        }
        if (more) {
            const int nb = buf ^ 1;
            As[nb][lc + 0][lr] = av.x;
            As[nb][lc + 1][lr] = av.y;
            As[nb][lc + 2][lr] = av.z;
            As[nb][lc + 3][lr] = av.w;
            Bs[nb][lc + 0][lr] = bv.x;
            Bs[nb][lc + 1][lr] = bv.y;
            Bs[nb][lc + 2][lr] = bv.z;
            Bs[nb][lc + 3][lr] = bv.w;
            __syncthreads();
        }
    }
#pragma unroll
    for (int i = 0; i < 8; ++i) {
        float4 o = make_float4(acc[i][0], acc[i][1], acc[i][2], acc[i][3]);
        *(float4*)(Cb + (size_t)(m0 + tm * 8 + i) * ldc + n0 + tn * 4) = o;
    }
}

// ---------------- K4: top-k per (token, head) ----------------
__global__ __launch_bounds__(512) void topk_k(const float* __restrict__ sim,
                                              int* __restrict__ eidx,
                                              float* __restrict__ gates) {
    int t = blockIdx.x;
    int h = threadIdx.x >> 6;
    int lane = threadIdx.x & 63;
    const float* s0p = sim + (size_t)t * 4096 + h * 256;
    const float* s1p = s0p + 2048;
    float4 v0 = *(const float4*)(s0p + lane * 4);
    float4 v1 = *(const float4*)(s1p + lane * 4);
    float c0[4] = {v0.x, v0.y, v0.z, v0.w};
    float c1[4] = {v1.x, v1.y, v1.z, v1.w};

    float tv0[8], tv1[8];
    int ti0[8], ti1[8];

#pragma unroll
    for (int r = 0; r < 8; ++r) {
        float bv = c0[0];
        int bi = lane * 4;
#pragma unroll
        for (int j = 1; j < 4; ++j)
            if (c0[j] > bv) { bv = c0[j]; bi = lane * 4 + j; }
#pragma unroll
        for (int off = 1; off < 64; off <<= 1) {
            float ov = __shfl_xor(bv, off);
            int oi = __shfl_xor(bi, off);
            if (ov > bv || (ov == bv && oi < bi)) { bv = ov; bi = oi; }
        }
        tv0[r] = bv;
        ti0[r] = bi;
        if ((bi >> 2) == lane) {
            int jj = bi & 3;
#pragma unroll
            for (int q = 0; q < 4; ++q)
                if (q == jj) c0[q] = -INFINITY;
        }
    }
#pragma unroll
    for (int r = 0; r < 8; ++r) {
        float bv = c1[0];
        int bi = lane * 4;
#pragma unroll
        for (int j = 1; j < 4; ++j)
            if (c1[j] > bv) { bv = c1[j]; bi = lane * 4 + j; }
#pragma unroll
        for (int off = 1; off < 64; off <<= 1) {
            float ov = __shfl_xor(bv, off);
            int oi = __shfl_xor(bi, off);
            if (ov > bv || (ov == bv && oi < bi)) { bv = ov; bi = oi; }
        }
        tv1[r] = bv;
        ti1[r] = bi;
        if ((bi >> 2) == lane) {
            int jj = bi & 3;
#pragma unroll
            for (int q = 0; q < 4; ++q)
                if (q == jj) c1[q] = -INFINITY;
        }
    }

    int ii = lane >> 3, jj = lane & 7;
    float a = -INFINITY, b = -INFINITY;
#pragma unroll
    for (int r = 0; r < 8; ++r) {
        if (ii == r) a = tv0[r];
        if (jj == r) b = tv1[r];
    }
    float cv = a + b;
    int cpos = lane;

    int outbase = (t * NHEAD + h) * KSEL;
#pragma unroll
    for (int r = 0; r < 8; ++r) {
        float bv = cv;
        int bp = cpos;
#pragma unroll
        for (int off = 1; off < 64; off <<= 1) {
            float ov = __shfl_xor(bv, off);
            int op = __shfl_xor(bp, off);
            if (ov > bv || (ov == bv && op < bp)) { bv = ov; bp = op; }
        }
        if (lane == 0) {
            int pi = bp >> 3, pj = bp & 7;
            int e0 = 0, e1 = 0;
#pragma unroll
            for (int q = 0; q < 8; ++q) {
                if (pi == q) e0 = ti0[q];
                if (pj == q) e1 = ti1[q];
            }
            eidx[outbase + r] = e0 * NKEY + e1;
            gates[outbase + r] = 1.0f / (1.0f + expf(-bv));
        }
        if (lane == bp) cv = -INFINITY;
    }
}

// ---------------- K5: expert gather + compute ----------------
// One block per token, 8 waves x 8 experts. Three phases per wave:
//  (1) streaming dot phase  (2) batched shuffle reduce + gelu/gate  (3) streaming up phase
__global__ __launch_bounds__(512, 2) void expert_k(const float* __restrict__ x,
                                                   const float* __restrict__ down,
                                                   const float* __restrict__ up,
                                                   const int* __restrict__ eidx,
                                                   const float* __restrict__ gates,
                                                   float* __restrict__ out) {
    int t = blockIdx.x;
    int w = threadIdx.x >> 6;      // 0..7
    int lane = threadIdx.x & 63;
    __shared__ __align__(16) float4 accs[8][256];

    const float4* x4 = (const float4*)(x + (size_t)t * HDIM);
    float4 xv[4];
#pragma unroll
    for (int j = 0; j < 4; ++j) xv[j] = x4[lane + 64 * j];

    int base = t * 64 + w * 8;
    int e[8];
    float g[8];
#pragma unroll
    for (int i = 0; i < 8; ++i) {
        e[i] = eidx[base + i];
        g[i] = gates[base + i];
    }

    float dot[8];
#pragma unroll
    for (int i = 0; i < 8; ++i) dot[i] = 0.f;
#pragma unroll
    for (int i = 0; i < 8; ++i) {
        const float4* d = (const float4*)(down + (size_t)e[i] * HDIM);
#pragma unroll
        for (int j = 0; j < 4; ++j) {
            float4 dv = d[lane + 64 * j];
            dot[i] += xv[j].x * dv.x + xv[j].y * dv.y + xv[j].z * dv.z + xv[j].w * dv.w;
        }
    }

#pragma unroll
    for (int off = 32; off >= 1; off >>= 1) {
#pragma unroll
        for (int i = 0; i < 8; ++i) dot[i] += __shfl_xor(dot[i], off);
    }
    float hm[8];
#pragma unroll
    for (int i = 0; i < 8; ++i) {
        float d = dot[i];
        hm[i] = g[i] * 0.5f * d * (1.0f + erff(d * 0.70710678118654752f));
    }

    float4 acc[4];
#pragma unroll
    for (int j = 0; j < 4; ++j) acc[j] = make_float4(0.f, 0.f, 0.f, 0.f);
#pragma unroll
    for (int i = 0; i < 8; ++i) {
        const float4* u = (const float4*)(up + (size_t)e[i] * HDIM);
        float h = hm[i];
#pragma unroll
        for (int j = 0; j < 4; ++j) {
            float4 uv = u[lane + 64 * j];
            acc[j].x = fmaf(h, uv.x, acc[j].x);
            acc[j].y = fmaf(h, uv.y, acc[j].y);
            acc[j].z = fmaf(h, uv.z, acc[j].z);
            acc[j].w = fmaf(h, uv.w, acc[j].w);
        }
    }

#pragma unroll
    for (int j = 0; j < 4; ++j) accs[w][lane + 64 * j] = acc[j];
    __syncthreads();
    if (threadIdx.x < 256) {
        int s = threadIdx.x;
        float4 o = accs[0][s];
#pragma unroll
        for (int ww = 1; ww < 8; ++ww) {
            float4 r = accs[ww][s];
            o.x += r.x; o.y += r.y; o.z += r.z; o.w += r.w;
        }
        ((float4*)(out + (size_t)t * HDIM))[s] = o;
    }
}

// ---------------- launch ----------------
extern "C" void kernel_launch(void* const* d_in, const int* in_sizes, int n_in,
                              void* d_out, int out_size, void* d_ws, size_t ws_size,
                              hipStream_t stream) {
    const float* x = (const float*)d_in[0];
    const float* gamma = (const float*)d_in[1];
    const float* beta = (const float*)d_in[2];
    const float* w_q = (const float*)d_in[3];
    const float* keys = (const float*)d_in[4];
    const float* down = (const float*)d_in[5];
    const float* up = (const float*)d_in[6];
    float* out = (float*)d_out;
    float* ws = (float*)d_ws;

    float* psum = ws;                       // 64*1024
    float* psq = ws + 65536;                // 64*1024
    float* scale = ws + 131072;             // 1024
    float* shift = ws + 132096;             // 1024
    float* q = ws + 262144;                 // 2048*2048 = 4194304
    float* sim = q + 4194304;               // 2048*4096 = 8388608
    int* eidx = (int*)(sim + 8388608);      // 2048*64
    float* gates = (float*)(eidx + 131072); // 2048*64

    bn_partial_k<<<64, 256, 0, stream>>>(x, psum, psq);
    bn_final_k<<<4, 256, 0, stream>>>(psum, psq, gamma, beta, scale, shift);
    gemm_k<0><<<dim3(16, 16, 1), 512, 0, stream>>>(x, w_q, q, scale, shift,
                                                   1024, 1024, 2048, 1024);
    gemm_k<1><<<dim3(16, 2, 16), 512, 0, stream>>>(q, keys, sim, nullptr, nullptr,
                                                   2048, 256, 4096, 128);
    topk_k<<<2048, 512, 0, stream>>>(sim, eidx, gates);
    expert_k<<<2048, 512, 0, stream>>>(x, down, up, eidx, gates, out);
}